// Round 9
// baseline (653.634 us; speedup 1.0000x reference)
//
#include <hip/hip_runtime.h>
#include <hip/hip_bf16.h>
#include <hip/hip_cooperative_groups.h>
#include <cstdint>
#include <cstddef>

namespace cg = cooperative_groups;

#define NROWS 16384
#define DDIM  256
// fallback (3-kernel) lse geometry
#define SPLITS 16
#define NTILES 256
#define TILES_PER (NTILES / SPLITS)
// fused cooperative geometry: 1024 blocks = 128 row-blocks x 8 splits
#define FGRID   1024
#define FSPLITS 8
#define FTILES  (NTILES / FSPLITS)   // 32 tiles per block

typedef __attribute__((ext_vector_type(4))) float f32x4;
typedef __attribute__((ext_vector_type(4))) float fl4;
typedef __attribute__((ext_vector_type(4))) int   i32x4;
typedef __attribute__((ext_vector_type(8))) int   i32x8;

constexpr float SCALE_EXP2 = 20.609929155556627f; // log2(e)/0.07 folded into qn
constexpr float LN2F       = 0.69314718055994531f;
constexpr float INV_T      = 14.285714285714286f;

__device__ inline void gload_lds16(const void* g, void* l) {
  __builtin_amdgcn_global_load_lds(
      (const __attribute__((address_space(1))) void*)g,
      (__attribute__((address_space(3))) void*)l, 16, 0, 0);
}

// ---------------- shared device bodies ----------------

// norm for one row (one wave): normalize q_i,k_i -> fp8 (q pre-scaled by
// log2(e)/T), fp32 diag_i, zero rowsum_i.
__device__ inline void norm_row(
    int row, int lane,
    const float* __restrict__ q, const float* __restrict__ k,
    unsigned char* __restrict__ qn, unsigned char* __restrict__ kn,
    float* __restrict__ diag, float* __restrict__ rowsum,
    float* __restrict__ out)
{
  const size_t off = (size_t)row * DDIM + lane * 4;
  fl4 vq = *(const fl4*)(q + off);
  fl4 vk = *(const fl4*)(k + off);
  float ssq = vq.x * vq.x + vq.y * vq.y + vq.z * vq.z + vq.w * vq.w;
  float ssk = vk.x * vk.x + vk.y * vk.y + vk.z * vk.z + vk.w * vk.w;
  float dot = vq.x * vk.x + vq.y * vk.y + vq.z * vk.z + vq.w * vk.w;
#pragma unroll
  for (int m = 1; m < 64; m <<= 1) {
    ssq += __shfl_xor(ssq, m, 64);
    ssk += __shfl_xor(ssk, m, 64);
    dot += __shfl_xor(dot, m, 64);
  }
  float rq = 1.0f / fmaxf(sqrtf(ssq), 1e-12f);
  float rk = 1.0f / fmaxf(sqrtf(ssk), 1e-12f);

  float sq = rq * SCALE_EXP2;
  int pq = __builtin_amdgcn_cvt_pk_fp8_f32(vq.x * sq, vq.y * sq, 0, false);
  pq     = __builtin_amdgcn_cvt_pk_fp8_f32(vq.z * sq, vq.w * sq, pq, true);
  *(int*)(qn + off) = pq;
  int pk = __builtin_amdgcn_cvt_pk_fp8_f32(vk.x * rk, vk.y * rk, 0, false);
  pk     = __builtin_amdgcn_cvt_pk_fp8_f32(vk.z * rk, vk.w * rk, pk, true);
  *(int*)(kn + off) = pk;

  if (lane == 0) {
    diag[row]   = dot * rq * rk * INV_T;
    rowsum[row] = 0.0f;
    if (row == 0) out[0] = 0.0f;
  }
}

// lse phase for one block: v2 structure (best measured: 71.8us), parameterized
// split/rb/tile-count. Bs = 2 x 16 KB double buffer.
// CRITICAL (R6 NaN post-mortem): __syncthreads() does NOT drain LDS-DMA vmcnt
// -- the explicit s_waitcnt(vmcnt) before it is required.
__device__ inline void lse_block(
    unsigned char (*Bs)[64 * DDIM],
    int split, int rb, int ntiles,
    const unsigned char* __restrict__ qn, const unsigned char* __restrict__ kn,
    float* __restrict__ rowsum)
{
  const int tid  = threadIdx.x;
  const int wave = tid >> 6, lane = tid & 63;
  const int l15  = lane & 15, quad = lane >> 4;
  const int wrow = rb * 128 + wave * 32;
  const int t0 = split * ntiles;
  const int t1 = t0 + ntiles;

  const int Ln = tid >> 4, Ljj = tid & 15;
  const int Lj = Ljj ^ Ln;
  const size_t src_off = (size_t)Ln * DDIM + (size_t)Lj * 16;

  i32x8 A00, A01, A10, A11;
  {
    const unsigned char* ap0 = qn + (size_t)(wrow + l15) * DDIM + quad * 32;
    const unsigned char* ap1 = qn + (size_t)(wrow + 16 + l15) * DDIM + quad * 32;
    A00 = *(const i32x8*)(ap0);
    A01 = *(const i32x8*)(ap0 + 128);
    A10 = *(const i32x8*)(ap1);
    A11 = *(const i32x8*)(ap1 + 128);
  }

  const int rowoff = l15 * DDIM;
  const int c0  = quad * 2;
  const int o00 = rowoff + (((c0    ) ^ l15) * 16);
  const int o01 = rowoff + (((c0 + 1) ^ l15) * 16);
  const int o10 = rowoff + (((c0 + 8) ^ l15) * 16);
  const int o11 = rowoff + (((c0 + 9) ^ l15) * 16);

  f32x4 sums0 = {0.f, 0.f, 0.f, 0.f}, sums1 = {0.f, 0.f, 0.f, 0.f};
  f32x4 accE0, accE1, accO0, accO1;
  accO0 = (f32x4){-1e30f, -1e30f, -1e30f, -1e30f};
  accO1 = accO0;

  {
    const unsigned char* kbase = kn + (size_t)t0 * (64 * DDIM) + src_off;
#pragma unroll
    for (int i = 0; i < 4; ++i)
      gload_lds16(kbase + i * 4096, (void*)(Bs[0] + tid * 16 + i * 4096));
  }

#define EPI(P0, P1) do {                                                      \
    f32x4 e0_, e1_;                                                           \
    e0_[0] = __builtin_amdgcn_exp2f(P0[0]);                                   \
    e0_[1] = __builtin_amdgcn_exp2f(P0[1]);                                   \
    e0_[2] = __builtin_amdgcn_exp2f(P0[2]);                                   \
    e0_[3] = __builtin_amdgcn_exp2f(P0[3]);                                   \
    e1_[0] = __builtin_amdgcn_exp2f(P1[0]);                                   \
    e1_[1] = __builtin_amdgcn_exp2f(P1[1]);                                   \
    e1_[2] = __builtin_amdgcn_exp2f(P1[2]);                                   \
    e1_[3] = __builtin_amdgcn_exp2f(P1[3]);                                   \
    sums0 += e0_;                                                             \
    sums1 += e1_;                                                             \
  } while (0)

#define CS_STEP(C, P, BOFF) do {                                              \
    i32x4 lo0_ = *(const i32x4*)(bb + (BOFF) + o00);                          \
    i32x4 hi0_ = *(const i32x4*)(bb + (BOFF) + o01);                          \
    i32x4 lo1_ = *(const i32x4*)(bb + (BOFF) + o10);                          \
    i32x4 hi1_ = *(const i32x4*)(bb + (BOFF) + o11);                          \
    EPI(P##0, P##1);                                                          \
    i32x8 b0_ = {lo0_.x, lo0_.y, lo0_.z, lo0_.w, hi0_.x, hi0_.y, hi0_.z, hi0_.w}; \
    i32x8 b1_ = {lo1_.x, lo1_.y, lo1_.z, lo1_.w, hi1_.x, hi1_.y, hi1_.z, hi1_.w}; \
    __builtin_amdgcn_s_setprio(1);                                            \
    C##0 = __builtin_amdgcn_mfma_scale_f32_16x16x128_f8f6f4(                  \
        A00, b0_, (f32x4){0.f, 0.f, 0.f, 0.f}, 0, 0, 0, 127, 0, 127);         \
    C##1 = __builtin_amdgcn_mfma_scale_f32_16x16x128_f8f6f4(                  \
        A10, b0_, (f32x4){0.f, 0.f, 0.f, 0.f}, 0, 0, 0, 127, 0, 127);         \
    C##0 = __builtin_amdgcn_mfma_scale_f32_16x16x128_f8f6f4(                  \
        A01, b1_, C##0, 0, 0, 0, 127, 0, 127);                                \
    C##1 = __builtin_amdgcn_mfma_scale_f32_16x16x128_f8f6f4(                  \
        A11, b1_, C##1, 0, 0, 0, 127, 0, 127);                                \
    __builtin_amdgcn_s_setprio(0);                                            \
  } while (0)

  for (int ct = t0; ct < t1; ++ct) {
    const int cur = (ct - t0) & 1;
    __builtin_amdgcn_s_waitcnt(0x0F70);  // vmcnt(0): drain buf[cur]'s LDS-DMA
    __syncthreads();
    if (ct + 1 < t1) {
      const unsigned char* kbase = kn + (size_t)(ct + 1) * (64 * DDIM) + src_off;
#pragma unroll
      for (int i = 0; i < 4; ++i)
        gload_lds16(kbase + i * 4096, (void*)(Bs[cur ^ 1] + tid * 16 + i * 4096));
    }
    const unsigned char* bb = Bs[cur];
    CS_STEP(accE, accO, 0);
    CS_STEP(accO, accE, 4096);
    CS_STEP(accE, accO, 8192);
    CS_STEP(accO, accE, 12288);
  }
  EPI(accO0, accO1);

#undef CS_STEP
#undef EPI

#pragma unroll
  for (int r = 0; r < 4; ++r) {
    float v0 = sums0[r], v1 = sums1[r];
    v0 += __shfl_xor(v0, 1, 64);  v1 += __shfl_xor(v1, 1, 64);
    v0 += __shfl_xor(v0, 2, 64);  v1 += __shfl_xor(v1, 2, 64);
    v0 += __shfl_xor(v0, 4, 64);  v1 += __shfl_xor(v1, 4, 64);
    v0 += __shfl_xor(v0, 8, 64);  v1 += __shfl_xor(v1, 8, 64);
    if (l15 == 0) {
      atomicAdd(&rowsum[wrow + quad * 4 + r], v0);
      atomicAdd(&rowsum[wrow + 16 + quad * 4 + r], v1);
    }
  }
}

// ---------------- fused cooperative kernel ----------------
// R8 post-mortem: dur_us - lse_dur is a CONSTANT ~60us across all 8 rounds
// (norm ~6us + final ~1us by roofline) -> ~55us/iter of inter-dispatch
// overhead. Fuse all three kernels: one cooperative launch, two grid syncs.
// 1024 blocks guaranteed co-resident (32KB LDS -> 5 blocks/CU >= 4 needed);
// lse phase gets guaranteed 4 blocks/CU (vs measured ~2.8) and FSPLITS=8
// gives each XCD exactly one split (512KB kn, L2-hot).
// Cross-XCD visibility (per-XCD L2s non-coherent): explicit __threadfence()
// (device-scope fence -> L2 wb/inv on gfx950) brackets each grid.sync();
// rowsum/out use device-scope atomics throughout.
__global__ __launch_bounds__(256) void fused_kernel(
    const float* __restrict__ q, const float* __restrict__ k,
    unsigned char* __restrict__ qn, unsigned char* __restrict__ kn,
    float* __restrict__ diag, float* __restrict__ rowsum,
    float* __restrict__ out)
{
  __shared__ __attribute__((aligned(16))) unsigned char Bs[2][64 * DDIM]; // 32 KB

  const int bid  = blockIdx.x;
  const int wave = threadIdx.x >> 6, lane = threadIdx.x & 63;
  cg::grid_group grid = cg::this_grid();

  // ---- phase 1: norm, 16 rows/block (wave w: rows base+w*4 .. +3)
  {
    const int base = bid * 16 + wave * 4;
#pragma unroll
    for (int r = 0; r < 4; ++r)
      norm_row(base + r, lane, q, k, qn, kn, diag, rowsum, out);
  }

  __threadfence();   // release qn/kn/diag/rowsum/out (L2 writeback)
  grid.sync();
  __threadfence();   // acquire (L2 invalidate) before reading remote writes

  // ---- phase 2: lse, split = bid&7 (== XCD id under round-robin dispatch)
  lse_block(Bs, bid & 7, bid >> 3, FTILES, qn, kn, rowsum);

  __threadfence();
  grid.sync();
  __threadfence();

  // ---- phase 3: final, 16 rows/block, lanes 0-15 of wave 0
  if (threadIdx.x < 16) {
    int row = bid * 16 + threadIdx.x;
    float c = __builtin_amdgcn_logf(rowsum[row]) * LN2F - diag[row];
    c += __shfl_xor(c, 1, 64);
    c += __shfl_xor(c, 2, 64);
    c += __shfl_xor(c, 4, 64);
    c += __shfl_xor(c, 8, 64);
    if (threadIdx.x == 0) atomicAdd(out, c * (1.0f / NROWS));
  }
}

// ---------------- fallback 3-kernel path (proven baseline) ----------------

__global__ __launch_bounds__(256) void norm_kernel(
    const float* __restrict__ q, const float* __restrict__ k,
    unsigned char* __restrict__ qn, unsigned char* __restrict__ kn,
    float* __restrict__ diag, float* __restrict__ rowsum,
    float* __restrict__ out)
{
  const int wave = threadIdx.x >> 6, lane = threadIdx.x & 63;
  norm_row(blockIdx.x * 4 + wave, lane, q, k, qn, kn, diag, rowsum, out);
}

__global__ __launch_bounds__(256) void lse_kernel(
    const unsigned char* __restrict__ qn, const unsigned char* __restrict__ kn,
    float* __restrict__ rowsum)
{
  __shared__ __attribute__((aligned(16))) unsigned char Bs[2][64 * DDIM];
  lse_block(Bs, blockIdx.x % SPLITS, blockIdx.x / SPLITS, TILES_PER, qn, kn, rowsum);
}

__global__ void final_kernel(const float* __restrict__ rowsum,
                             const float* __restrict__ diag,
                             float* __restrict__ out)
{
  int row = blockIdx.x * 256 + threadIdx.x;
  float c = __builtin_amdgcn_logf(rowsum[row]) * LN2F - diag[row];
#pragma unroll
  for (int m = 1; m < 64; m <<= 1) c += __shfl_xor(c, m, 64);
  __shared__ float red[4];
  int wave = threadIdx.x >> 6, lane = threadIdx.x & 63;
  if (lane == 0) red[wave] = c;
  __syncthreads();
  if (threadIdx.x == 0) {
    float s = red[0] + red[1] + red[2] + red[3];
    atomicAdd(out, s * (1.0f / NROWS));
  }
}

extern "C" void kernel_launch(void* const* d_in, const int* in_sizes, int n_in,
                              void* d_out, int out_size, void* d_ws, size_t ws_size,
                              hipStream_t stream)
{
  const float* q = (const float*)d_in[0];
  const float* k = (const float*)d_in[1];
  float* out = (float*)d_out;

  char* ws = (char*)d_ws;
  unsigned char* qn = (unsigned char*)ws;                    // 4 MB
  unsigned char* kn = (unsigned char*)(ws + (4u << 20));     // 4 MB
  float* diag   = (float*)(ws + (8u << 20));                 // 64 KB
  float* rowsum = (float*)(ws + (8u << 20) + (64u << 10));   // 64 KB

  void* args[] = {(void*)&q, (void*)&k, (void*)&qn, (void*)&kn,
                  (void*)&diag, (void*)&rowsum, (void*)&out};
  hipError_t e = hipLaunchCooperativeKernel(
      reinterpret_cast<void*>(fused_kernel), dim3(FGRID), dim3(256),
      args, 0, stream);
  if (e != hipSuccess) {
    (void)hipGetLastError();  // clear, fall back to proven 3-kernel path
    norm_kernel <<<NROWS / 4, 256, 0, stream>>>(q, k, qn, kn, diag, rowsum, out);
    lse_kernel  <<<(NROWS / 128) * SPLITS, 256, 0, stream>>>(qn, kn, rowsum);
    final_kernel<<<NROWS / 256, 256, 0, stream>>>(rowsum, diag, out);
  }
}